// Round 1
// baseline (2579.913 us; speedup 1.0000x reference)
//
#include <hip/hip_runtime.h>
#include <hip/hip_bf16.h>

#define D_MODEL   640
#define D_INNER   1280
#define D_STATE   34
#define D_CONV    4
#define DT_RANK   40
#define BATCH     2
#define SEQ       2048
#define XDBL_W    (DT_RANK + 2 * D_STATE)   // 108
#define M_TOTAL   (BATCH * SEQ)             // 4096

// ---------------------------------------------------------------------------
// Generic f32 TN GEMM: C[M,N] = A[M,K(lda)] * B[N,K(ldb)]^T
// 64x64 tile, 256 threads, 4x4 per thread, BK=16.
// ---------------------------------------------------------------------------
#define BM 64
#define BN 64
#define BK 16

__global__ __launch_bounds__(256) void gemm_tn(
    const float* __restrict__ A, const float* __restrict__ B,
    float* __restrict__ C, int M, int N, int K, int lda, int ldb, int ldc)
{
    __shared__ float As[BK][BM + 4];
    __shared__ float Bs[BK][BN + 4];

    const int tid = threadIdx.x;
    const int m0 = blockIdx.y * BM;
    const int n0 = blockIdx.x * BN;
    const int tx = tid & 15;          // 0..15 -> n
    const int ty = tid >> 4;          // 0..15 -> m

    float acc[4][4] = {};

    for (int k0 = 0; k0 < K; k0 += BK) {
        // cooperative load of A-tile (64x16) and B-tile (64x16), coalesced in k
        #pragma unroll
        for (int i = 0; i < 4; ++i) {
            int idx = tid + i * 256;
            int r = idx >> 4;          // 0..63 (row within tile)
            int c = idx & 15;          // 0..15 (k within tile)
            int gk = k0 + c;
            int gm = m0 + r;
            int gn = n0 + r;
            As[c][r] = (gm < M && gk < K) ? A[(long)gm * lda + gk] : 0.0f;
            Bs[c][r] = (gn < N && gk < K) ? B[(long)gn * ldb + gk] : 0.0f;
        }
        __syncthreads();

        #pragma unroll
        for (int k = 0; k < BK; ++k) {
            const float4 a4 = *reinterpret_cast<const float4*>(&As[k][ty * 4]);
            const float4 b4 = *reinterpret_cast<const float4*>(&Bs[k][tx * 4]);
            const float a_[4] = {a4.x, a4.y, a4.z, a4.w};
            const float b_[4] = {b4.x, b4.y, b4.z, b4.w};
            #pragma unroll
            for (int i = 0; i < 4; ++i)
                #pragma unroll
                for (int j = 0; j < 4; ++j)
                    acc[i][j] = fmaf(a_[i], b_[j], acc[i][j]);
        }
        __syncthreads();
    }

    #pragma unroll
    for (int i = 0; i < 4; ++i) {
        int gm = m0 + ty * 4 + i;
        if (gm >= M) continue;
        #pragma unroll
        for (int j = 0; j < 4; ++j) {
            int gn = n0 + tx * 4 + j;
            if (gn < N) C[(long)gm * ldc + gn] = acc[i][j];
        }
    }
}

// ---------------------------------------------------------------------------
// Depthwise causal conv (width 4) + bias + SiLU.
// Reads the x-half of xz (layout [b*S+s][2560]), writes xc [b*S+s][1280].
// ---------------------------------------------------------------------------
__global__ __launch_bounds__(256) void conv_silu_kernel(
    const float* __restrict__ xz, const float* __restrict__ cw,
    const float* __restrict__ cb, float* __restrict__ xc)
{
    int idx = blockIdx.x * 256 + threadIdx.x;      // (b*S+s)*1280 + d
    if (idx >= BATCH * SEQ * D_INNER) return;
    int d  = idx % D_INNER;
    int bs = idx / D_INNER;                        // b*S + s
    int s  = bs % SEQ;

    float acc = cb[d];
    #pragma unroll
    for (int k = 0; k < D_CONV; ++k) {
        int ss = s - (D_CONV - 1) + k;
        if (ss >= 0)
            acc = fmaf(xz[(long)(bs - (D_CONV - 1) + k) * (2 * D_INNER) + d],
                       cw[d * D_CONV + k], acc);
    }
    xc[idx] = acc * (1.0f / (1.0f + __expf(-acc)));
}

// ---------------------------------------------------------------------------
// Selective scan: one wave per (b, d) channel, lane = state index n (n<34).
// Fuses softplus(dt+bias), dA=exp, h update, y reduction, D-skip, z-SiLU gate.
// Writes y in-place over xc (safe: element read before written by same wave).
// ---------------------------------------------------------------------------
__global__ __launch_bounds__(256) void scan_kernel(
    const float* __restrict__ xz,      // z at [bs*2560 + 1280 + d]
    const float* __restrict__ xdbl,    // B at [bs*108 + 40 + n], C at [.. + 74 + n]
    const float* __restrict__ dtbuf,   // raw dt [bs*1280 + d]
    const float* __restrict__ dt_bias,
    const float* __restrict__ A_log,
    const float* __restrict__ D_skip,
    float* __restrict__ xc_y)          // in: u, out: y
{
    const int wave = blockIdx.x * 4 + (threadIdx.x >> 6);
    const int lane = threadIdx.x & 63;
    const int b = wave / D_INNER;
    const int d = wave % D_INNER;
    const bool act = lane < D_STATE;

    const float A_n  = act ? -__expf(A_log[d * D_STATE + lane]) : 0.0f;
    const float bias = dt_bias[d];
    const float Dd   = D_skip[d];

    const float* z_p  = xz    + (long)b * SEQ * (2 * D_INNER) + D_INNER + d;
    const float* bc_p = xdbl  + (long)b * SEQ * XDBL_W;
    const float* dt_p = dtbuf + (long)b * SEQ * D_INNER + d;
    float*       u_p  = xc_y  + (long)b * SEQ * D_INNER + d;

    float h = 0.0f;

    // preload t = 0
    float dtv = dt_p[0];
    float uv  = u_p[0];
    float zv  = z_p[0];
    float Bn  = act ? bc_p[DT_RANK + lane] : 0.0f;
    float Cn  = act ? bc_p[DT_RANK + D_STATE + lane] : 0.0f;

    for (int t = 0; t < SEQ; ++t) {
        // issue next-step loads early (hides L2 latency under compute)
        float dt2 = 0.f, u2 = 0.f, z2 = 0.f, B2 = 0.f, C2 = 0.f;
        if (t + 1 < SEQ) {
            dt2 = dt_p[(long)(t + 1) * D_INNER];
            u2  = u_p [(long)(t + 1) * D_INNER];
            z2  = z_p [(long)(t + 1) * (2 * D_INNER)];
            if (act) {
                B2 = bc_p[(long)(t + 1) * XDBL_W + DT_RANK + lane];
                C2 = bc_p[(long)(t + 1) * XDBL_W + DT_RANK + D_STATE + lane];
            }
        }

        float x  = dtv + bias;
        float sp = (x > 15.0f) ? x : log1pf(__expf(x));   // softplus
        float dA = __expf(sp * A_n);                      // A_n <= 0
        h = fmaf(dA, h, sp * uv * Bn);
        float p = h * Cn;

        #pragma unroll
        for (int off = 32; off; off >>= 1) p += __shfl_xor(p, off);

        if (lane == 0) {
            float y = fmaf(uv, Dd, p);
            float sg = 1.0f / (1.0f + __expf(-zv));
            u_p[(long)t * D_INNER] = y * zv * sg;
        }

        dtv = dt2; uv = u2; zv = z2; Bn = B2; Cn = C2;
    }
}

// ---------------------------------------------------------------------------
extern "C" void kernel_launch(void* const* d_in, const int* in_sizes, int n_in,
                              void* d_out, int out_size, void* d_ws, size_t ws_size,
                              hipStream_t stream)
{
    const float* hs      = (const float*)d_in[0];
    const float* W_in    = (const float*)d_in[1];
    const float* conv_w  = (const float*)d_in[2];
    const float* conv_b  = (const float*)d_in[3];
    const float* W_x     = (const float*)d_in[4];
    const float* W_dt    = (const float*)d_in[5];
    const float* dt_bias = (const float*)d_in[6];
    const float* A_log   = (const float*)d_in[7];
    const float* D_skip  = (const float*)d_in[8];
    const float* W_out   = (const float*)d_in[9];
    float* out = (float*)d_out;

    float* ws   = (float*)d_ws;
    float* xz   = ws;                                        // 4096 x 2560
    float* xc   = xz   + (size_t)M_TOTAL * 2 * D_INNER;      // 4096 x 1280 (u, then y)
    float* xdbl = xc   + (size_t)M_TOTAL * D_INNER;          // 4096 x 108
    float* dtb  = xdbl + (size_t)M_TOTAL * XDBL_W;           // 4096 x 1280

    dim3 blk(256);

    // 1) xz = hs @ W_in^T
    gemm_tn<<<dim3((2 * D_INNER + BN - 1) / BN, M_TOTAL / BM), blk, 0, stream>>>(
        hs, W_in, xz, M_TOTAL, 2 * D_INNER, D_MODEL, D_MODEL, D_MODEL, 2 * D_INNER);

    // 2) x = silu(dwconv(x) + b)
    conv_silu_kernel<<<(M_TOTAL * D_INNER + 255) / 256, blk, 0, stream>>>(
        xz, conv_w, conv_b, xc);

    // 3) x_dbl = x @ W_x^T
    gemm_tn<<<dim3((XDBL_W + BN - 1) / BN, M_TOTAL / BM), blk, 0, stream>>>(
        xc, W_x, xdbl, M_TOTAL, XDBL_W, D_INNER, D_INNER, D_INNER, XDBL_W);

    // 4) dt = dt_raw @ W_dt^T   (dt_raw = x_dbl[:, :40], lda = 108)
    gemm_tn<<<dim3((D_INNER + BN - 1) / BN, M_TOTAL / BM), blk, 0, stream>>>(
        xdbl, W_dt, dtb, M_TOTAL, D_INNER, DT_RANK, XDBL_W, DT_RANK, D_INNER);

    // 5) selective scan (fuses softplus, D-skip, z-gate); y overwrites xc
    scan_kernel<<<(BATCH * D_INNER) / 4, blk, 0, stream>>>(
        xz, xdbl, dtb, dt_bias, A_log, D_skip, xc);

    // 6) out = y @ W_out^T
    gemm_tn<<<dim3((D_MODEL + BN - 1) / BN, M_TOTAL / BM), blk, 0, stream>>>(
        xc, W_out, out, M_TOTAL, D_MODEL, D_INNER, D_INNER, D_INNER, D_MODEL);
}

// Round 2
// 1322.049 us; speedup vs baseline: 1.9515x; 1.9515x over previous
//
#include <hip/hip_runtime.h>
#include <hip/hip_bf16.h>

#define D_MODEL   640
#define D_INNER   1280
#define D_STATE   34
#define D_CONV    4
#define DT_RANK   40
#define BATCH     2
#define SEQ       2048
#define XDBL_W    (DT_RANK + 2 * D_STATE)   // 108
#define M_TOTAL   (BATCH * SEQ)             // 4096

// ---------------------------------------------------------------------------
// Generic f32 TN GEMM: C[M,N] = A[M,K(lda)] * B[N,K(ldb)]^T
// 64x64 tile, 256 threads, 4x4 per thread, BK=16.
// epilogue mode: 0 = none, 1 = softplus(acc + bias[n])
// ---------------------------------------------------------------------------
#define BM 64
#define BN 64
#define BK 16

__global__ __launch_bounds__(256) void gemm_tn(
    const float* __restrict__ A, const float* __restrict__ B,
    float* __restrict__ C, int M, int N, int K, int lda, int ldb, int ldc,
    const float* __restrict__ bias, int mode)
{
    __shared__ float As[BK][BM + 4];
    __shared__ float Bs[BK][BN + 4];

    const int tid = threadIdx.x;
    const int m0 = blockIdx.y * BM;
    const int n0 = blockIdx.x * BN;
    const int tx = tid & 15;          // 0..15 -> n
    const int ty = tid >> 4;          // 0..15 -> m

    float acc[4][4] = {};

    for (int k0 = 0; k0 < K; k0 += BK) {
        #pragma unroll
        for (int i = 0; i < 4; ++i) {
            int idx = tid + i * 256;
            int r = idx >> 4;          // 0..63 (row within tile)
            int c = idx & 15;          // 0..15 (k within tile)
            int gk = k0 + c;
            int gm = m0 + r;
            int gn = n0 + r;
            As[c][r] = (gm < M && gk < K) ? A[(long)gm * lda + gk] : 0.0f;
            Bs[c][r] = (gn < N && gk < K) ? B[(long)gn * ldb + gk] : 0.0f;
        }
        __syncthreads();

        #pragma unroll
        for (int k = 0; k < BK; ++k) {
            const float4 a4 = *reinterpret_cast<const float4*>(&As[k][ty * 4]);
            const float4 b4 = *reinterpret_cast<const float4*>(&Bs[k][tx * 4]);
            const float a_[4] = {a4.x, a4.y, a4.z, a4.w};
            const float b_[4] = {b4.x, b4.y, b4.z, b4.w};
            #pragma unroll
            for (int i = 0; i < 4; ++i)
                #pragma unroll
                for (int j = 0; j < 4; ++j)
                    acc[i][j] = fmaf(a_[i], b_[j], acc[i][j]);
        }
        __syncthreads();
    }

    #pragma unroll
    for (int i = 0; i < 4; ++i) {
        int gm = m0 + ty * 4 + i;
        if (gm >= M) continue;
        #pragma unroll
        for (int j = 0; j < 4; ++j) {
            int gn = n0 + tx * 4 + j;
            if (gn >= N) continue;
            float v = acc[i][j];
            if (mode == 1) {
                v += bias[gn];
                v = (v > 15.0f) ? v : log1pf(__expf(v));   // softplus
            }
            C[(long)gm * ldc + gn] = v;
        }
    }
}

// ---------------------------------------------------------------------------
// Depthwise causal conv (width 4) + bias + SiLU.
// ---------------------------------------------------------------------------
__global__ __launch_bounds__(256) void conv_silu_kernel(
    const float* __restrict__ xz, const float* __restrict__ cw,
    const float* __restrict__ cb, float* __restrict__ xc)
{
    int idx = blockIdx.x * 256 + threadIdx.x;      // (b*S+s)*1280 + d
    if (idx >= BATCH * SEQ * D_INNER) return;
    int d  = idx % D_INNER;
    int bs = idx / D_INNER;                        // b*S + s
    int s  = bs % SEQ;

    float acc = cb[d];
    #pragma unroll
    for (int k = 0; k < D_CONV; ++k) {
        int ss = s - (D_CONV - 1) + k;
        if (ss >= 0)
            acc = fmaf(xz[(long)(bs - (D_CONV - 1) + k) * (2 * D_INNER) + d],
                       cw[d * D_CONV + k], acc);
    }
    xc[idx] = acc * (1.0f / (1.0f + __expf(-acc)));
}

// ---------------------------------------------------------------------------
// Selective scan, v2: one wave per (b, d) channel, lane = state index n.
// dt input is PRE-SOFTPLUSED (fused into the dt GEMM epilogue).
// Deep register prefetch: double-buffered 8-step FIFO, fully unrolled so all
// register indices are compile-time (runtime-indexed reg arrays -> scratch).
// ---------------------------------------------------------------------------
#define PF 8

__global__ __launch_bounds__(64) void scan_kernel(
    const float* __restrict__ xz,      // z at [bs*2560 + 1280 + d]
    const float* __restrict__ xdbl,    // B at [bs*108 + 40 + n], C at [.. + 74 + n]
    const float* __restrict__ spbuf,   // softplus(dt + bias)  [bs*1280 + d]
    const float* __restrict__ A_log,
    const float* __restrict__ D_skip,
    float* __restrict__ xc_y)          // in: u, out: y (in-place)
{
    const int wave = blockIdx.x;
    const int lane = threadIdx.x;      // 0..63
    const int b = wave / D_INNER;
    const int d = wave % D_INNER;
    const bool act = lane < D_STATE;

    const float A_n = act ? -__expf(A_log[d * D_STATE + lane]) : 0.0f;
    const float Dd  = D_skip[d];

    const float* z_p  = xz    + (long)b * SEQ * (2 * D_INNER) + D_INNER + d;
    const float* bc_p = xdbl  + (long)b * SEQ * XDBL_W;
    const float* sp_p = spbuf + (long)b * SEQ * D_INNER + d;
    float*       u_p  = xc_y  + (long)b * SEQ * D_INNER + d;

    float h = 0.0f;

    float aSP[PF], aU[PF], aZ[PF], aB[PF], aC[PF];
    float bSP[PF], bU[PF], bZ[PF], bB[PF], bC[PF];

#define LOADS(SP_, U_, Z_, B_, C_, T_) {                                     \
        int tt = (T_); tt = (tt < SEQ) ? tt : (SEQ - 1);                     \
        SP_ = sp_p[(long)tt * D_INNER];                                      \
        U_  = u_p [(long)tt * D_INNER];                                      \
        Z_  = z_p [(long)tt * (2 * D_INNER)];                                \
        const float* bcq = bc_p + (long)tt * XDBL_W + DT_RANK + lane;        \
        B_ = act ? bcq[0]       : 0.0f;                                      \
        C_ = act ? bcq[D_STATE] : 0.0f;                                      \
    }

#define STEP(SP_, U_, Z_, B_, C_, T_) {                                      \
        float dA = __expf(SP_ * A_n);                                        \
        h = fmaf(dA, h, (SP_ * U_) * B_);                                    \
        float pp = h * C_;                                                   \
        pp += __shfl_xor(pp, 32); pp += __shfl_xor(pp, 16);                  \
        pp += __shfl_xor(pp, 8);  pp += __shfl_xor(pp, 4);                   \
        pp += __shfl_xor(pp, 2);  pp += __shfl_xor(pp, 1);                   \
        if (lane == 0) {                                                     \
            float y  = fmaf(U_, Dd, pp);                                     \
            float sg = Z_ / (1.0f + __expf(-Z_));                            \
            u_p[(long)(T_) * D_INNER] = y * sg;                              \
        }                                                                    \
    }

    #pragma unroll
    for (int i = 0; i < PF; ++i) LOADS(aSP[i], aU[i], aZ[i], aB[i], aC[i], i);

    for (int t0 = 0; t0 < SEQ; t0 += 2 * PF) {
        #pragma unroll
        for (int i = 0; i < PF; ++i)
            LOADS(bSP[i], bU[i], bZ[i], bB[i], bC[i], t0 + PF + i);
        #pragma unroll
        for (int i = 0; i < PF; ++i)
            STEP(aSP[i], aU[i], aZ[i], aB[i], aC[i], t0 + i);
        #pragma unroll
        for (int i = 0; i < PF; ++i)
            LOADS(aSP[i], aU[i], aZ[i], aB[i], aC[i], t0 + 2 * PF + i);
        #pragma unroll
        for (int i = 0; i < PF; ++i)
            STEP(bSP[i], bU[i], bZ[i], bB[i], bC[i], t0 + PF + i);
    }
#undef LOADS
#undef STEP
}

// ---------------------------------------------------------------------------
extern "C" void kernel_launch(void* const* d_in, const int* in_sizes, int n_in,
                              void* d_out, int out_size, void* d_ws, size_t ws_size,
                              hipStream_t stream)
{
    const float* hs      = (const float*)d_in[0];
    const float* W_in    = (const float*)d_in[1];
    const float* conv_w  = (const float*)d_in[2];
    const float* conv_b  = (const float*)d_in[3];
    const float* W_x     = (const float*)d_in[4];
    const float* W_dt    = (const float*)d_in[5];
    const float* dt_bias = (const float*)d_in[6];
    const float* A_log   = (const float*)d_in[7];
    const float* D_skip  = (const float*)d_in[8];
    const float* W_out   = (const float*)d_in[9];
    float* out = (float*)d_out;

    float* ws   = (float*)d_ws;
    float* xz   = ws;                                        // 4096 x 2560
    float* xc   = xz   + (size_t)M_TOTAL * 2 * D_INNER;      // 4096 x 1280 (u, then y)
    float* xdbl = xc   + (size_t)M_TOTAL * D_INNER;          // 4096 x 108
    float* spb  = xdbl + (size_t)M_TOTAL * XDBL_W;           // 4096 x 1280 (softplus dt)

    dim3 blk(256);

    // 1) xz = hs @ W_in^T
    gemm_tn<<<dim3((2 * D_INNER + BN - 1) / BN, M_TOTAL / BM), blk, 0, stream>>>(
        hs, W_in, xz, M_TOTAL, 2 * D_INNER, D_MODEL, D_MODEL, D_MODEL, 2 * D_INNER,
        nullptr, 0);

    // 2) x = silu(dwconv(x) + b)
    conv_silu_kernel<<<(M_TOTAL * D_INNER + 255) / 256, blk, 0, stream>>>(
        xz, conv_w, conv_b, xc);

    // 3) x_dbl = x @ W_x^T
    gemm_tn<<<dim3((XDBL_W + BN - 1) / BN, M_TOTAL / BM), blk, 0, stream>>>(
        xc, W_x, xdbl, M_TOTAL, XDBL_W, D_INNER, D_INNER, D_INNER, XDBL_W,
        nullptr, 0);

    // 4) sp = softplus(dt_raw @ W_dt^T + dt_bias)   (fused epilogue)
    gemm_tn<<<dim3((D_INNER + BN - 1) / BN, M_TOTAL / BM), blk, 0, stream>>>(
        xdbl, W_dt, spb, M_TOTAL, D_INNER, DT_RANK, XDBL_W, DT_RANK, D_INNER,
        dt_bias, 1);

    // 5) selective scan (fused D-skip + z-gate); y overwrites xc.
    //    One wave per (b,d) channel -> 2560 single-wave blocks (even CU spread).
    scan_kernel<<<BATCH * D_INNER, 64, 0, stream>>>(
        xz, xdbl, spb, A_log, D_skip, xc);

    // 6) out = y @ W_out^T
    gemm_tn<<<dim3((D_MODEL + BN - 1) / BN, M_TOTAL / BM), blk, 0, stream>>>(
        xc, W_out, out, M_TOTAL, D_MODEL, D_INNER, D_INNER, D_INNER, D_MODEL,
        nullptr, 0);
}

// Round 3
// 1245.122 us; speedup vs baseline: 2.0720x; 1.0618x over previous
//
#include <hip/hip_runtime.h>
#include <hip/hip_bf16.h>

#define D_MODEL   640
#define D_INNER   1280
#define D_STATE   34
#define D_CONV    4
#define DT_RANK   40
#define BATCH     2
#define SEQ       2048
#define XDBL_W    (DT_RANK + 2 * D_STATE)   // 108
#define M_TOTAL   (BATCH * SEQ)             // 4096

// ---------------------------------------------------------------------------
// f32 GEMM: C[M,N] = A.B^T with A either [M,K] (LAYA=0) or [K,M] (LAYA=1).
// B is always [N,K]. 64x64 tile, 256 threads, 4x4 per thread, BK=16.
// MODE: 0 = none, 1 = silu(v), 2 = softplus(v + bias[gm])
// ---------------------------------------------------------------------------
#define BM 64
#define BN 64
#define BK 16

template<int LAYA, int MODE>
__global__ __launch_bounds__(256) void gemm_tn(
    const float* __restrict__ A, const float* __restrict__ B,
    float* __restrict__ C, int M, int N, int K, int lda, int ldb, int ldc,
    const float* __restrict__ bias)
{
    __shared__ float As[BK][BM + 4];
    __shared__ float Bs[BK][BN + 4];

    const int tid = threadIdx.x;
    const int m0 = blockIdx.y * BM;
    const int n0 = blockIdx.x * BN;
    const int tx = tid & 15;          // 0..15 -> n
    const int ty = tid >> 4;          // 0..15 -> m

    float acc[4][4] = {};

    for (int k0 = 0; k0 < K; k0 += BK) {
        #pragma unroll
        for (int i = 0; i < 4; ++i) {
            int idx = tid + i * 256;
            if (LAYA == 0) {
                int r = idx >> 4;          // m row 0..63
                int c = idx & 15;          // k   0..15
                As[c][r] = (m0 + r < M && k0 + c < K)
                         ? A[(long)(m0 + r) * lda + (k0 + c)] : 0.0f;
            } else {
                int c = idx >> 6;          // k   0..15
                int r = idx & 63;          // m   0..63 (contiguous -> coalesced)
                As[c][r] = (m0 + r < M && k0 + c < K)
                         ? A[(long)(k0 + c) * lda + (m0 + r)] : 0.0f;
            }
            int rb = idx >> 4;
            int cb = idx & 15;
            Bs[cb][rb] = (n0 + rb < N && k0 + cb < K)
                       ? B[(long)(n0 + rb) * ldb + (k0 + cb)] : 0.0f;
        }
        __syncthreads();

        #pragma unroll
        for (int k = 0; k < BK; ++k) {
            const float4 a4 = *reinterpret_cast<const float4*>(&As[k][ty * 4]);
            const float4 b4 = *reinterpret_cast<const float4*>(&Bs[k][tx * 4]);
            const float a_[4] = {a4.x, a4.y, a4.z, a4.w};
            const float b_[4] = {b4.x, b4.y, b4.z, b4.w};
            #pragma unroll
            for (int i = 0; i < 4; ++i)
                #pragma unroll
                for (int j = 0; j < 4; ++j)
                    acc[i][j] = fmaf(a_[i], b_[j], acc[i][j]);
        }
        __syncthreads();
    }

    #pragma unroll
    for (int i = 0; i < 4; ++i) {
        int gm = m0 + ty * 4 + i;
        if (gm >= M) continue;
        float bi = (MODE == 2) ? bias[gm] : 0.0f;
        #pragma unroll
        for (int j = 0; j < 4; ++j) {
            int gn = n0 + tx * 4 + j;
            if (gn >= N) continue;
            float v = acc[i][j];
            if (MODE == 1) v = v * (1.0f / (1.0f + __expf(-v)));
            if (MODE == 2) {
                v += bi;
                v = (v > 15.0f) ? v : log1pf(__expf(v));   // softplus
            }
            C[(long)gm * ldc + gn] = v;
        }
    }
}

// ---------------------------------------------------------------------------
// Depthwise causal conv (width 4) + bias + SiLU on TRANSPOSED x [1280][4096].
// Fully coalesced: consecutive threads -> consecutive s within one d-row.
// ---------------------------------------------------------------------------
__global__ __launch_bounds__(256) void conv_silu_kernel(
    const float* __restrict__ xT, const float* __restrict__ cw,
    const float* __restrict__ cb, float* __restrict__ uT)
{
    int idx = blockIdx.x * 256 + threadIdx.x;      // d*4096 + bs
    if (idx >= D_INNER * M_TOTAL) return;
    int bs = idx & (M_TOTAL - 1);
    int d  = idx >> 12;                            // /4096 (wave-uniform)
    int s  = bs & (SEQ - 1);

    const float* xr = xT + idx;
    float acc = cb[d];
    #pragma unroll
    for (int k = 0; k < D_CONV; ++k) {
        int off = k - (D_CONV - 1);                // -3..0
        if (s + off >= 0)
            acc = fmaf(xr[off], cw[d * D_CONV + k], acc);
    }
    uT[idx] = acc * (1.0f / (1.0f + __expf(-acc)));
}

// ---------------------------------------------------------------------------
// Selective scan v3, all streams transposed [1280][4096] (contiguous in t).
// One wave per (b,d); lane = state n. dt pre-softplused, z pre-gated (g=silu z).
// Double-buffered 8-step register FIFO, fully unrolled (static reg indices).
// ---------------------------------------------------------------------------
#define PF 8

__global__ __launch_bounds__(64) void scan_kernel(
    const float* __restrict__ gT,      // silu(z)          [1280][4096]
    const float* __restrict__ xdbl,    // B/C at [bs*108 + 40(+34) + n]
    const float* __restrict__ spT,     // softplus(dt+bias)[1280][4096]
    const float* __restrict__ A_log,
    const float* __restrict__ D_skip,
    float* __restrict__ uT)            // in: u, out: y*g (in-place)
{
    const int wave = blockIdx.x;
    const int lane = threadIdx.x;      // 0..63
    const int b = wave / D_INNER;
    const int d = wave % D_INNER;
    const bool act = lane < D_STATE;

    const float A_n = act ? -__expf(A_log[d * D_STATE + lane]) : 0.0f;
    const float Dd  = D_skip[d];

    const long base = (long)d * M_TOTAL + (long)b * SEQ;
    const float* sp_p = spT + base;
    const float* g_p  = gT  + base;
    float*       u_p  = uT  + base;
    const float* bc_p = xdbl + (long)b * SEQ * XDBL_W;

    float h = 0.0f;

    float aSP[PF], aU[PF], aG[PF], aB[PF], aC[PF];
    float bSP[PF], bU[PF], bG[PF], bB[PF], bC[PF];

#define LOADS(SP_, U_, G_, B_, C_, T_) {                                     \
        int tt = (T_); tt = (tt < SEQ) ? tt : (SEQ - 1);                     \
        SP_ = sp_p[tt];                                                      \
        U_  = u_p [tt];                                                      \
        G_  = g_p [tt];                                                      \
        const float* bcq = bc_p + (long)tt * XDBL_W + DT_RANK + lane;        \
        B_ = act ? bcq[0]       : 0.0f;                                      \
        C_ = act ? bcq[D_STATE] : 0.0f;                                      \
    }

#define STEP(SP_, U_, G_, B_, C_, T_) {                                      \
        float dA = __expf(SP_ * A_n);                                        \
        h = fmaf(dA, h, (SP_ * U_) * B_);                                    \
        float pp = h * C_;                                                   \
        pp += __shfl_xor(pp, 32); pp += __shfl_xor(pp, 16);                  \
        pp += __shfl_xor(pp, 8);  pp += __shfl_xor(pp, 4);                   \
        pp += __shfl_xor(pp, 2);  pp += __shfl_xor(pp, 1);                   \
        if (lane == 0) {                                                     \
            float y = fmaf(U_, Dd, pp);                                      \
            u_p[T_] = y * G_;                                                \
        }                                                                    \
    }

    #pragma unroll
    for (int i = 0; i < PF; ++i) LOADS(aSP[i], aU[i], aG[i], aB[i], aC[i], i);

    for (int t0 = 0; t0 < SEQ; t0 += 2 * PF) {
        #pragma unroll
        for (int i = 0; i < PF; ++i)
            LOADS(bSP[i], bU[i], bG[i], bB[i], bC[i], t0 + PF + i);
        #pragma unroll
        for (int i = 0; i < PF; ++i)
            STEP(aSP[i], aU[i], aG[i], aB[i], aC[i], t0 + i);
        #pragma unroll
        for (int i = 0; i < PF; ++i)
            LOADS(aSP[i], aU[i], aG[i], aB[i], aC[i], t0 + 2 * PF + i);
        #pragma unroll
        for (int i = 0; i < PF; ++i)
            STEP(bSP[i], bU[i], bG[i], bB[i], bC[i], t0 + PF + i);
    }
#undef LOADS
#undef STEP
}

// ---------------------------------------------------------------------------
extern "C" void kernel_launch(void* const* d_in, const int* in_sizes, int n_in,
                              void* d_out, int out_size, void* d_ws, size_t ws_size,
                              hipStream_t stream)
{
    const float* hs      = (const float*)d_in[0];
    const float* W_in    = (const float*)d_in[1];
    const float* conv_w  = (const float*)d_in[2];
    const float* conv_b  = (const float*)d_in[3];
    const float* W_x     = (const float*)d_in[4];
    const float* W_dt    = (const float*)d_in[5];
    const float* dt_bias = (const float*)d_in[6];
    const float* A_log   = (const float*)d_in[7];
    const float* D_skip  = (const float*)d_in[8];
    const float* W_out   = (const float*)d_in[9];
    float* out = (float*)d_out;

    float* ws   = (float*)d_ws;
    float* xT   = ws;                                        // 1280 x 4096
    float* gT   = xT   + (size_t)D_INNER * M_TOTAL;          // 1280 x 4096
    float* uT   = gT   + (size_t)D_INNER * M_TOTAL;          // 1280 x 4096 (u, then y)
    float* xdbl = uT   + (size_t)D_INNER * M_TOTAL;          // 4096 x 108
    float* spT  = xdbl + (size_t)M_TOTAL * XDBL_W;           // 1280 x 4096

    dim3 blk(256);

    // 1a) x_T = W_in[:1280] @ hs^T        [1280][4096]
    gemm_tn<0, 0><<<dim3(M_TOTAL / BN, D_INNER / BM), blk, 0, stream>>>(
        W_in, hs, xT, D_INNER, M_TOTAL, D_MODEL, D_MODEL, D_MODEL, M_TOTAL, nullptr);

    // 1b) g_T = silu(W_in[1280:] @ hs^T)  [1280][4096]
    gemm_tn<0, 1><<<dim3(M_TOTAL / BN, D_INNER / BM), blk, 0, stream>>>(
        W_in + (size_t)D_INNER * D_MODEL, hs, gT, D_INNER, M_TOTAL, D_MODEL,
        D_MODEL, D_MODEL, M_TOTAL, nullptr);

    // 2) u_T = silu(dwconv(x_T) + cb)     [1280][4096]
    conv_silu_kernel<<<(D_INNER * M_TOTAL + 255) / 256, blk, 0, stream>>>(
        xT, conv_w, conv_b, uT);

    // 3) x_dbl = u @ W_x^T                [4096][108]   (A = u_T, K-major)
    gemm_tn<1, 0><<<dim3((XDBL_W + BN - 1) / BN, M_TOTAL / BM), blk, 0, stream>>>(
        uT, W_x, xdbl, M_TOTAL, XDBL_W, D_INNER, M_TOTAL, D_INNER, XDBL_W, nullptr);

    // 4) sp_T = softplus(W_dt @ dt_raw^T + bias)  [1280][4096]
    gemm_tn<0, 2><<<dim3(M_TOTAL / BN, D_INNER / BM), blk, 0, stream>>>(
        W_dt, xdbl, spT, D_INNER, M_TOTAL, DT_RANK, DT_RANK, XDBL_W, M_TOTAL,
        dt_bias);

    // 5) selective scan (fused D-skip + pre-gated z); y overwrites u_T.
    scan_kernel<<<BATCH * D_INNER, 64, 0, stream>>>(
        gT, xdbl, spT, A_log, D_skip, uT);

    // 6) out = y @ W_out^T                [4096][640]   (A = y_T, K-major)
    gemm_tn<1, 0><<<dim3(D_MODEL / BN, M_TOTAL / BM), blk, 0, stream>>>(
        uT, W_out, out, M_TOTAL, D_MODEL, D_INNER, M_TOTAL, D_INNER, D_MODEL,
        nullptr);
}

// Round 4
// 973.744 us; speedup vs baseline: 2.6495x; 1.2787x over previous
//
#include <hip/hip_runtime.h>
#include <hip/hip_bf16.h>

#define D_MODEL   640
#define D_INNER   1280
#define D_STATE   34
#define D_CONV    4
#define DT_RANK   40
#define BATCH     2
#define SEQ       2048
#define XDBL_W    (DT_RANK + 2 * D_STATE)   // 108
#define M_TOTAL   (BATCH * SEQ)             // 4096

// ---------------------------------------------------------------------------
// f32 GEMM: C[M,N] = A.B^T with A either [M,K] (LAYA=0) or [K,M] (LAYA=1).
// B is always [N,K]. 64x64 tile, 256 threads, 4x4 per thread, BK=16.
// MODE: 0 = none, 1 = silu(v), 2 = softplus(v + bias[gm])
// ---------------------------------------------------------------------------
#define BM 64
#define BN 64
#define BK 16

template<int LAYA, int MODE>
__global__ __launch_bounds__(256) void gemm_tn(
    const float* __restrict__ A, const float* __restrict__ B,
    float* __restrict__ C, int M, int N, int K, int lda, int ldb, int ldc,
    const float* __restrict__ bias)
{
    __shared__ float As[BK][BM + 4];
    __shared__ float Bs[BK][BN + 4];

    const int tid = threadIdx.x;
    const int m0 = blockIdx.y * BM;
    const int n0 = blockIdx.x * BN;
    const int tx = tid & 15;          // 0..15 -> n
    const int ty = tid >> 4;          // 0..15 -> m

    float acc[4][4] = {};

    for (int k0 = 0; k0 < K; k0 += BK) {
        #pragma unroll
        for (int i = 0; i < 4; ++i) {
            int idx = tid + i * 256;
            if (LAYA == 0) {
                int r = idx >> 4;          // m row 0..63
                int c = idx & 15;          // k   0..15
                As[c][r] = (m0 + r < M && k0 + c < K)
                         ? A[(long)(m0 + r) * lda + (k0 + c)] : 0.0f;
            } else {
                int c = idx >> 6;          // k   0..15
                int r = idx & 63;          // m   0..63 (contiguous -> coalesced)
                As[c][r] = (m0 + r < M && k0 + c < K)
                         ? A[(long)(k0 + c) * lda + (m0 + r)] : 0.0f;
            }
            int rb = idx >> 4;
            int cb = idx & 15;
            Bs[cb][rb] = (n0 + rb < N && k0 + cb < K)
                       ? B[(long)(n0 + rb) * ldb + (k0 + cb)] : 0.0f;
        }
        __syncthreads();

        #pragma unroll
        for (int k = 0; k < BK; ++k) {
            const float4 a4 = *reinterpret_cast<const float4*>(&As[k][ty * 4]);
            const float4 b4 = *reinterpret_cast<const float4*>(&Bs[k][tx * 4]);
            const float a_[4] = {a4.x, a4.y, a4.z, a4.w};
            const float b_[4] = {b4.x, b4.y, b4.z, b4.w};
            #pragma unroll
            for (int i = 0; i < 4; ++i)
                #pragma unroll
                for (int j = 0; j < 4; ++j)
                    acc[i][j] = fmaf(a_[i], b_[j], acc[i][j]);
        }
        __syncthreads();
    }

    #pragma unroll
    for (int i = 0; i < 4; ++i) {
        int gm = m0 + ty * 4 + i;
        if (gm >= M) continue;
        float bi = (MODE == 2) ? bias[gm] : 0.0f;
        #pragma unroll
        for (int j = 0; j < 4; ++j) {
            int gn = n0 + tx * 4 + j;
            if (gn >= N) continue;
            float v = acc[i][j];
            if (MODE == 1) v = v * (1.0f / (1.0f + __expf(-v)));
            if (MODE == 2) {
                v += bi;
                v = (v > 15.0f) ? v : log1pf(__expf(v));   // softplus
            }
            C[(long)gm * ldc + gn] = v;
        }
    }
}

// ---------------------------------------------------------------------------
// Depthwise causal conv (width 4) + bias + SiLU on TRANSPOSED x [1280][4096].
// ---------------------------------------------------------------------------
__global__ __launch_bounds__(256) void conv_silu_kernel(
    const float* __restrict__ xT, const float* __restrict__ cw,
    const float* __restrict__ cb, float* __restrict__ uT)
{
    int idx = blockIdx.x * 256 + threadIdx.x;      // d*4096 + bs
    if (idx >= D_INNER * M_TOTAL) return;
    int bs = idx & (M_TOTAL - 1);
    int d  = idx >> 12;                            // /4096 (wave-uniform)
    int s  = bs & (SEQ - 1);

    const float* xr = xT + idx;
    float acc = cb[d];
    #pragma unroll
    for (int k = 0; k < D_CONV; ++k) {
        int off = k - (D_CONV - 1);                // -3..0
        if (s + off >= 0)
            acc = fmaf(xr[off], cw[d * D_CONV + k], acc);
    }
    uT[idx] = acc * (1.0f / (1.0f + __expf(-acc)));
}

// ---------------------------------------------------------------------------
// Selective scan v4: DPP-based wave reduction (VALU pipe, no LDS ops).
// row_shr 1/2/4/8 + row_bcast 15/31 -> full 64-lane sum lands in lane 63.
// Streams transposed [1280][4096]; dt pre-softplused; z pre-gated.
// ---------------------------------------------------------------------------
#define PF 8

__device__ __forceinline__ float dpp_add(float x, float acc_src, int /*unused*/) {
    return x; // placeholder (not used)
}

#define DPP_ADD(X_, CTRL_) {                                                 \
        int t_ = __builtin_amdgcn_update_dpp(                                \
            0, __builtin_bit_cast(int, X_), (CTRL_), 0xf, 0xf, true);        \
        X_ += __builtin_bit_cast(float, t_);                                 \
    }

__global__ __launch_bounds__(64) void scan_kernel(
    const float* __restrict__ gT,      // silu(z)          [1280][4096]
    const float* __restrict__ xdbl,    // B/C at [bs*108 + 40(+34) + n]
    const float* __restrict__ spT,     // softplus(dt+bias)[1280][4096]
    const float* __restrict__ A_log,
    const float* __restrict__ D_skip,
    float* __restrict__ uT)            // in: u, out: y*g (in-place)
{
    const int wave = blockIdx.x;
    const int lane = threadIdx.x;      // 0..63
    const int b = wave / D_INNER;
    const int d = wave % D_INNER;
    const bool act = lane < D_STATE;

    const float A_n = act ? -__expf(A_log[d * D_STATE + lane]) : 0.0f;
    const float Dd  = D_skip[d];

    const long base = (long)d * M_TOTAL + (long)b * SEQ;
    const float* sp_p = spT + base;
    const float* g_p  = gT  + base;
    float*       u_p  = uT  + base;
    const float* bc_p = xdbl + (long)b * SEQ * XDBL_W;

    float h = 0.0f;

    float aSP[PF], aU[PF], aG[PF], aB[PF], aC[PF];
    float bSP[PF], bU[PF], bG[PF], bB[PF], bC[PF];

#define LOADS(SP_, U_, G_, B_, C_, T_) {                                     \
        int tt = (T_); tt = (tt < SEQ) ? tt : (SEQ - 1);                     \
        SP_ = sp_p[tt];                                                      \
        U_  = u_p [tt];                                                      \
        G_  = g_p [tt];                                                      \
        const float* bcq = bc_p + (long)tt * XDBL_W + DT_RANK + lane;        \
        B_ = act ? bcq[0]       : 0.0f;                                      \
        C_ = act ? bcq[D_STATE] : 0.0f;                                      \
    }

#define STEP(SP_, U_, G_, B_, C_, T_) {                                      \
        float dA = __expf(SP_ * A_n);                                        \
        h = fmaf(dA, h, (SP_ * U_) * B_);                                    \
        float pp = h * C_;                                                   \
        DPP_ADD(pp, 0x111);   /* row_shr:1  */                               \
        DPP_ADD(pp, 0x112);   /* row_shr:2  */                               \
        DPP_ADD(pp, 0x114);   /* row_shr:4  */                               \
        DPP_ADD(pp, 0x118);   /* row_shr:8  */                               \
        DPP_ADD(pp, 0x142);   /* row_bcast:15 */                             \
        DPP_ADD(pp, 0x143);   /* row_bcast:31 */                             \
        if (lane == 63) {                                                    \
            float y = fmaf(U_, Dd, pp);                                      \
            u_p[T_] = y * G_;                                                \
        }                                                                    \
    }

    #pragma unroll
    for (int i = 0; i < PF; ++i) LOADS(aSP[i], aU[i], aG[i], aB[i], aC[i], i);

    for (int t0 = 0; t0 < SEQ; t0 += 2 * PF) {
        #pragma unroll
        for (int i = 0; i < PF; ++i)
            LOADS(bSP[i], bU[i], bG[i], bB[i], bC[i], t0 + PF + i);
        #pragma unroll
        for (int i = 0; i < PF; ++i)
            STEP(aSP[i], aU[i], aG[i], aB[i], aC[i], t0 + i);
        #pragma unroll
        for (int i = 0; i < PF; ++i)
            LOADS(aSP[i], aU[i], aG[i], aB[i], aC[i], t0 + 2 * PF + i);
        #pragma unroll
        for (int i = 0; i < PF; ++i)
            STEP(bSP[i], bU[i], bG[i], bB[i], bC[i], t0 + PF + i);
    }
#undef LOADS
#undef STEP
}

// ---------------------------------------------------------------------------
extern "C" void kernel_launch(void* const* d_in, const int* in_sizes, int n_in,
                              void* d_out, int out_size, void* d_ws, size_t ws_size,
                              hipStream_t stream)
{
    const float* hs      = (const float*)d_in[0];
    const float* W_in    = (const float*)d_in[1];
    const float* conv_w  = (const float*)d_in[2];
    const float* conv_b  = (const float*)d_in[3];
    const float* W_x     = (const float*)d_in[4];
    const float* W_dt    = (const float*)d_in[5];
    const float* dt_bias = (const float*)d_in[6];
    const float* A_log   = (const float*)d_in[7];
    const float* D_skip  = (const float*)d_in[8];
    const float* W_out   = (const float*)d_in[9];
    float* out = (float*)d_out;

    float* ws   = (float*)d_ws;
    float* xT   = ws;                                        // 1280 x 4096
    float* gT   = xT   + (size_t)D_INNER * M_TOTAL;          // 1280 x 4096
    float* uT   = gT   + (size_t)D_INNER * M_TOTAL;          // 1280 x 4096 (u, then y)
    float* xdbl = uT   + (size_t)D_INNER * M_TOTAL;          // 4096 x 108
    float* spT  = xdbl + (size_t)M_TOTAL * XDBL_W;           // 1280 x 4096

    dim3 blk(256);

    // 1a) x_T = W_in[:1280] @ hs^T        [1280][4096]
    gemm_tn<0, 0><<<dim3(M_TOTAL / BN, D_INNER / BM), blk, 0, stream>>>(
        W_in, hs, xT, D_INNER, M_TOTAL, D_MODEL, D_MODEL, D_MODEL, M_TOTAL, nullptr);

    // 1b) g_T = silu(W_in[1280:] @ hs^T)  [1280][4096]
    gemm_tn<0, 1><<<dim3(M_TOTAL / BN, D_INNER / BM), blk, 0, stream>>>(
        W_in + (size_t)D_INNER * D_MODEL, hs, gT, D_INNER, M_TOTAL, D_MODEL,
        D_MODEL, D_MODEL, M_TOTAL, nullptr);

    // 2) u_T = silu(dwconv(x_T) + cb)     [1280][4096]
    conv_silu_kernel<<<(D_INNER * M_TOTAL + 255) / 256, blk, 0, stream>>>(
        xT, conv_w, conv_b, uT);

    // 3) x_dbl = u @ W_x^T                [4096][108]   (A = u_T, K-major)
    gemm_tn<1, 0><<<dim3((XDBL_W + BN - 1) / BN, M_TOTAL / BM), blk, 0, stream>>>(
        uT, W_x, xdbl, M_TOTAL, XDBL_W, D_INNER, M_TOTAL, D_INNER, XDBL_W, nullptr);

    // 4) sp_T = softplus(W_dt @ dt_raw^T + bias)  [1280][4096]
    gemm_tn<0, 2><<<dim3(M_TOTAL / BN, D_INNER / BM), blk, 0, stream>>>(
        W_dt, xdbl, spT, D_INNER, M_TOTAL, DT_RANK, DT_RANK, XDBL_W, M_TOTAL,
        dt_bias);

    // 5) selective scan (fused D-skip + pre-gated z); y overwrites u_T.
    scan_kernel<<<BATCH * D_INNER, 64, 0, stream>>>(
        gT, xdbl, spT, A_log, D_skip, uT);

    // 6) out = y @ W_out^T                [4096][640]   (A = y_T, K-major)
    gemm_tn<1, 0><<<dim3(D_MODEL / BN, M_TOTAL / BM), blk, 0, stream>>>(
        uT, W_out, out, M_TOTAL, D_MODEL, D_INNER, M_TOTAL, D_INNER, D_MODEL,
        nullptr);
}